// Round 8
// baseline (503.751 us; speedup 1.0000x reference)
//
#include <hip/hip_runtime.h>
#include <hip/hip_fp16.h>
#include <math.h>

#define N_NODES 200000
#define N_EDGES 6400000
#define T 6
#define M 10

// CSR build configuration: 256-node buckets, chunked counting sort.
#define NB    782            // ceil(200000/256) buckets (dst>>8)
#define NBLK  256            // edge chunks == CU count
#define CH    25000          // edges per chunk (256*25000 = 6.4M exact)
#define GHLEN (NB * NBLK)    // 200192

#define SBLOCKS 196          // ceil(GHLEN/1024) scan blocks

// passC dynamic LDS: edge array (CH) + cnt/ls/lcur/gs (4*NB) + scan buf (1024)
#define PASSC_LDS_INTS  (CH + 4 * NB + 1024)
#define PASSC_LDS_BYTES (PASSC_LDS_INTS * 4)   // 116,608 B < 160 KiB/CU

#define QSCALE  262144.0f    // 2^18 signed fixed-point (round 0; |sum| small)
#define QINV    (1.0f / 262144.0f)
#define PSCALE  512.0f       // u16-pair fixed point (fp8 rounds, values in (0,1))
#define PINV    (1.0f / 512.0f)

typedef __attribute__((ext_vector_type(2))) float vf2;
typedef __attribute__((ext_vector_type(4))) unsigned int u32x4;

// ---------------------------------------------------------------------------
// Pass A (+ fused convert): per-chunk bucket histogram -> gh[bucket*NBLK+g],
// and x_member [N,6] fp32 -> xh [N,8] fp16 conversion (grid 256x1024 covers
// all 200k nodes in one stride; saves a kernel launch).
// ---------------------------------------------------------------------------
__global__ __launch_bounds__(1024) void passA_kernel(
    const int* __restrict__ dst, int* __restrict__ gh,
    const float* __restrict__ x, __half* __restrict__ xh)
{
    __shared__ int lh[NB];
    int g   = blockIdx.x;
    int tid = threadIdx.x;

    // fused convert: 256*1024 = 262144 >= N_NODES, single stride
    int i = g * 1024 + tid;
    if (i < N_NODES) {
        const vf2* p = (const vf2*)(x + (size_t)i * 6);   // rows 24B, 8B aligned
        vf2 a = __builtin_nontemporal_load(p);
        vf2 b = __builtin_nontemporal_load(p + 1);
        vf2 c = __builtin_nontemporal_load(p + 2);
        union { __half2 h[4]; u32x4 q; } u;
        u.h[0] = __floats2half2_rn(a.x, a.y);
        u.h[1] = __floats2half2_rn(b.x, b.y);
        u.h[2] = __floats2half2_rn(c.x, c.y);
        u.h[3] = __floats2half2_rn(0.f, 0.f);
        __builtin_nontemporal_store(u.q, (u32x4*)(xh + (size_t)i * 8));
    }

    for (int t = tid; t < NB; t += 1024) lh[t] = 0;
    __syncthreads();
    int base = g * CH;
    int end  = base + CH; if (end > N_EDGES) end = N_EDGES;
    for (int e = base + tid; e < end; e += 1024)
        atomicAdd(&lh[__builtin_nontemporal_load(dst + e) >> 8], 1);
    __syncthreads();
    for (int t = tid; t < NB; t += 1024) gh[t * NBLK + g] = lh[t];
}

// ---------------------------------------------------------------------------
// Hierarchical exclusive scan of gh[GHLEN].
// scan3 DELETED: consumers add bsum[idx>>10] themselves.
// ---------------------------------------------------------------------------
__global__ __launch_bounds__(1024) void scan1_kernel(
    int* __restrict__ gh, int* __restrict__ bsum)
{
    __shared__ int sbuf[1024];
    int tid = threadIdx.x;
    int t   = blockIdx.x * 1024 + tid;
    int v   = (t < GHLEN) ? gh[t] : 0;
    sbuf[tid] = v;
    __syncthreads();
    for (int d = 1; d < 1024; d <<= 1) {
        int u = (tid >= d) ? sbuf[tid - d] : 0;
        __syncthreads();
        sbuf[tid] += u;
        __syncthreads();
    }
    if (t < GHLEN) gh[t] = sbuf[tid] - v;           // local exclusive
    if (tid == 1023) bsum[blockIdx.x] = sbuf[1023]; // block total
}

__global__ __launch_bounds__(256) void scan2_kernel(int* __restrict__ bsum)
{
    __shared__ int sbuf[256];
    int tid = threadIdx.x;
    int v = (tid < SBLOCKS) ? bsum[tid] : 0;
    sbuf[tid] = v;
    __syncthreads();
    for (int d = 1; d < 256; d <<= 1) {
        int u = (tid >= d) ? sbuf[tid - d] : 0;
        __syncthreads();
        sbuf[tid] += u;
        __syncthreads();
    }
    if (tid < SBLOCKS) bsum[tid] = sbuf[tid] - v;   // exclusive
}

// ---------------------------------------------------------------------------
// Pass C: counting-sort the whole chunk INSIDE LDS, then copy each
// (bucket,chunk) segment out as a contiguous per-wave burst (full-line,
// write-once; scattered 4 B stores cost 5.9x write amp at HBM).
// ---------------------------------------------------------------------------
__global__ __launch_bounds__(1024) void passC_kernel(
    const int* __restrict__ src, const int* __restrict__ dst,
    const int* __restrict__ gh, const int* __restrict__ bsum,
    int* __restrict__ ebuf)
{
    extern __shared__ int dyn[];
    int* earr = dyn;             // [CH]  bucket-sorted packed edges
    int* cnt  = dyn + CH;        // [NB]  edges of bucket b in this chunk
    int* ls   = cnt + NB;        // [NB]  local exclusive start
    int* lcur = ls + NB;         // [NB]  scatter cursor
    int* gs   = lcur + NB;       // [NB]  global segment start
    int* sbuf = gs + NB;         // [1024] scan temp

    int g   = blockIdx.x;
    int tid = threadIdx.x;

    // per-bucket global start + count for this chunk (bsum fold: no scan3)
    for (int b = tid; b < NB; b += 1024) {
        int idx = b * NBLK + g;
        int s0  = gh[idx] + bsum[idx >> 10];
        int s1  = (idx + 1 < GHLEN) ? gh[idx + 1] + bsum[(idx + 1) >> 10]
                                    : N_EDGES;
        gs[b]  = s0;
        cnt[b] = s1 - s0;
    }
    __syncthreads();

    // exclusive scan of cnt -> ls (NB=782 <= 1024, single pass)
    int v = (tid < NB) ? cnt[tid] : 0;
    sbuf[tid] = v;
    __syncthreads();
    for (int d = 1; d < 1024; d <<= 1) {
        int u = (tid >= d) ? sbuf[tid - d] : 0;
        __syncthreads();
        sbuf[tid] += u;
        __syncthreads();
    }
    if (tid < NB) { int e0 = sbuf[tid] - v; ls[tid] = e0; lcur[tid] = e0; }
    __syncthreads();

    // scatter chunk edges into LDS, bucket-grouped (LDS atomics only)
    int base = g * CH;
    for (int e = base + tid; e < base + CH; e += 1024) {
        int s = __builtin_nontemporal_load(src + e);
        int d = __builtin_nontemporal_load(dst + e);
        int b = d >> 8;
        int p = atomicAdd(&lcur[b], 1);
        earr[p] = (s << 8) | (d & 255);
    }
    __syncthreads();

    // coalesced copy-out: one wave per bucket segment (mean 32 edges = 128 B)
    int wv = tid >> 6, lane = tid & 63;
    for (int b = wv; b < NB; b += 16) {
        int bl = ls[b], bg = gs[b], c = cnt[b];
        for (int o = lane; o < c; o += 64)
            ebuf[bg + o] = earr[bl + o];   // normal store: L2 merges the
    }                                      // chunk-boundary-shared lines
}

// ---------------------------------------------------------------------------
// round, v7: scatter-accumulate with NT gathers.
//
// r6/r7 evidence: gather path saturated (~4.9 cyc/16B txn), occupancy- AND
// ILP-insensitive (r6 4-deep/40% vs r7 8-deep/26%: same time). New theory:
// the wall is L1 LINE-FILL bandwidth — 3.2 MB table vs 32 KB L1 -> ~1% hit
// rate; every miss fills a 128 B line, uses 16 B (8x waste). FIX UNDER TEST:
// __builtin_nontemporal_load on the in[] gathers (nt -> no L1 allocation,
// served from L2). Kill-criterion: FETCH_SIZE >100 MB = nt bypassed L2 too
// -> revert. Structure otherwise = r6's 4-deep (VGPR ~30, occ ~40%) + r7's
// verified u16-pair packed atomics (fp8 rounds: 5 atomics/edge; conflicts
// halved 5.06M->2.53M) + direct __shared__ atomics (r4 lesson).
// ---------------------------------------------------------------------------
template<int TD, bool FP8IN>
__device__ __forceinline__ void decode_row(u32x4 q, float* f)
{
    if (FP8IN) {
        vf2 f0 = __builtin_amdgcn_cvt_pk_f32_fp8(q.x, false);
        vf2 f1 = __builtin_amdgcn_cvt_pk_f32_fp8(q.x, true);
        vf2 f2 = __builtin_amdgcn_cvt_pk_f32_fp8(q.y, false);
        vf2 f3 = __builtin_amdgcn_cvt_pk_f32_fp8(q.y, true);
        vf2 f4 = __builtin_amdgcn_cvt_pk_f32_fp8(q.z, false);
        f[0] = f0.x; f[1] = f0.y; f[2] = f1.x; f[3] = f1.y;
        f[4] = f2.x; f[5] = f2.y; f[6] = f3.x; f[7] = f3.y;
        f[8] = f4.x; f[9] = f4.y;
    } else {
        union { u32x4 q; __half2 h[8]; } u; u.q = q;
#pragma unroll
        for (int k = 0; k < TD / 2; ++k) {
            float2 d = __half22float2(u.h[k]);
            f[2 * k] = d.x; f[2 * k + 1] = d.y;
        }
    }
}

// register-only: decode a row and produce the QST packed addends
template<int TD, bool FP8IN, int QST>
__device__ __forceinline__ void pack_row(u32x4 q, unsigned int* pk)
{
    float f[TD];
    decode_row<TD, FP8IN>(q, f);
    if (FP8IN) {
#pragma unroll
        for (int k = 0; k < 5; ++k)
            pk[k] = __float2uint_rn(f[2 * k] * PSCALE)
                  | (__float2uint_rn(f[2 * k + 1] * PSCALE) << 16);
    } else {
#pragma unroll
        for (int t = 0; t < TD; ++t)
            pk[t] = (unsigned int)__float2int_rn(f[t] * QSCALE);
    }
}

template<int TD, bool FP8IN>
__global__ __launch_bounds__(512) void round_kernel(
    const u32x4* __restrict__ in,      // [N] 16 B rows (fp16x8 or fp8x16)
    const int*   __restrict__ gh,      // scanned (bucket,chunk) offsets (local)
    const int*   __restrict__ bsum,    // scan block offsets (scan3 folded)
    const int*   __restrict__ col,     // packed (src<<8)|dstlow, bucket-grouped
    u32x4*       __restrict__ rout,    // [N] 16 B fp8 rows
    const float* __restrict__ H,       // [TD, M]
    const float* __restrict__ Wsc, int widx,
    float*       __restrict__ facc)
{
    constexpr int QST = FP8IN ? 5 : 7;     // ints per node (gcd(QST,32)=1)
    __shared__ unsigned int qacc[256 * QST];
    __shared__ int   shb[2];
    __shared__ float lsm[8][M];

    int b   = blockIdx.x;
    int tid = threadIdx.x;

    for (int k = tid; k < 256 * QST; k += 512) qacc[k] = 0u;
    if (tid == 0) {
        int i0 = b * NBLK;
        shb[0] = gh[i0] + bsum[i0 >> 10];
        if (b == NB - 1) shb[1] = N_EDGES;
        else {
            int i1 = (b + 1) * NBLK;
            shb[1] = gh[i1] + bsum[i1 >> 10];
        }
    }
    __syncthreads();
    int e0 = shb[0], e1 = shb[1];
    int e0a = (e0 + 3) & ~3;            // align for dwordx4
    if (e0a > e1) e0a = e1;
    int nvec = (e1 - e0a) >> 2;

    // head (<=3 edges)
    for (int k = e0 + tid; k < e0a; k += 512) {
        int e = __builtin_nontemporal_load(col + k);
        u32x4 q = __builtin_nontemporal_load(in + (e >> 8));
        unsigned int pk[QST];
        pack_row<TD, FP8IN, QST>(q, pk);
        int a0 = (e & 255) * QST;
#pragma unroll
        for (int t = 0; t < QST; ++t) atomicAdd(&qacc[a0 + t], pk[t]);
    }
    // main: 4 packed edges per lane-iter, 4 NT gathers in flight
    const u32x4* colv = (const u32x4*)(col + e0a);
    for (int g = tid; g < nvec; g += 512) {
        u32x4 ee = __builtin_nontemporal_load(colv + g);
        int ex = (int)ee.x, ey = (int)ee.y, ez = (int)ee.z, ew = (int)ee.w;
        u32x4 q0 = __builtin_nontemporal_load(in + (ex >> 8));
        u32x4 q1 = __builtin_nontemporal_load(in + (ey >> 8));
        u32x4 q2 = __builtin_nontemporal_load(in + (ez >> 8));
        u32x4 q3 = __builtin_nontemporal_load(in + (ew >> 8));
        unsigned int pk[QST];
        pack_row<TD, FP8IN, QST>(q0, pk);
        int a0 = (ex & 255) * QST;
#pragma unroll
        for (int t = 0; t < QST; ++t) atomicAdd(&qacc[a0 + t], pk[t]);
        pack_row<TD, FP8IN, QST>(q1, pk);
        a0 = (ey & 255) * QST;
#pragma unroll
        for (int t = 0; t < QST; ++t) atomicAdd(&qacc[a0 + t], pk[t]);
        pack_row<TD, FP8IN, QST>(q2, pk);
        a0 = (ez & 255) * QST;
#pragma unroll
        for (int t = 0; t < QST; ++t) atomicAdd(&qacc[a0 + t], pk[t]);
        pack_row<TD, FP8IN, QST>(q3, pk);
        a0 = (ew & 255) * QST;
#pragma unroll
        for (int t = 0; t < QST; ++t) atomicAdd(&qacc[a0 + t], pk[t]);
    }
    // tail (<=3 edges)
    for (int k = e0a + nvec * 4 + tid; k < e1; k += 512) {
        int e = __builtin_nontemporal_load(col + k);
        u32x4 q = __builtin_nontemporal_load(in + (e >> 8));
        unsigned int pk[QST];
        pack_row<TD, FP8IN, QST>(q, pk);
        int a0 = (e & 255) * QST;
#pragma unroll
        for (int t = 0; t < QST; ++t) atomicAdd(&qacc[a0 + t], pk[t]);
    }
    __syncthreads();

    float w = Wsc[widx];
    float sm[M];
    int i = b * 256 + tid;

    if (tid < 256 && i < N_NODES) {
        float self[TD];
        decode_row<TD, FP8IN>(in[i], self);
        float v[TD];
        if (FP8IN) {
#pragma unroll
            for (int k = 0; k < 5; ++k) {
                unsigned int q = qacc[tid * QST + k];
                v[2 * k]     = (float)(q & 0xFFFFu) * PINV + self[2 * k];
                v[2 * k + 1] = (float)(q >> 16)     * PINV + self[2 * k + 1];
            }
        } else {
#pragma unroll
            for (int t = 0; t < TD; ++t)
                v[t] = (float)(int)qacc[tid * QST + t] * QINV + self[t];
        }

        float z[M];
#pragma unroll
        for (int m = 0; m < M; ++m) {
            float a = 0.0f;
#pragma unroll
            for (int t = 0; t < TD; ++t) a += v[t] * H[t * M + m];
            z[m] = a;
        }
        float rr[M];
        float ssum = 0.0f;
#pragma unroll
        for (int m = 0; m < M; ++m) {
            rr[m] = 1.0f / (1.0f + __expf(-z[m]));
            sm[m] = __expf(rr[m] * w);            // rr*w in (0,0.2): no max shift
            ssum += sm[m];
        }
        {
            int d0 = __builtin_amdgcn_cvt_pk_fp8_f32(rr[0], rr[1], 0, false);
            d0     = __builtin_amdgcn_cvt_pk_fp8_f32(rr[2], rr[3], d0, true);
            int d1 = __builtin_amdgcn_cvt_pk_fp8_f32(rr[4], rr[5], 0, false);
            d1     = __builtin_amdgcn_cvt_pk_fp8_f32(rr[6], rr[7], d1, true);
            int d2 = __builtin_amdgcn_cvt_pk_fp8_f32(rr[8], rr[9], 0, false);
            u32x4 o = { (unsigned)d0, (unsigned)d1, (unsigned)d2, 0u };
            __builtin_nontemporal_store(o, rout + i);
        }
        float inv = 1.0f / ssum;
#pragma unroll
        for (int m = 0; m < M; ++m) sm[m] *= inv;
    } else {
#pragma unroll
        for (int m = 0; m < M; ++m) sm[m] = 0.0f;
    }

    // wave-64 shuffle reduction of the 10 softmax sums (8 waves)
#pragma unroll
    for (int m = 0; m < M; ++m) {
        float x = sm[m];
#pragma unroll
        for (int o = 32; o > 0; o >>= 1) x += __shfl_down(x, o);
        sm[m] = x;
    }
    int lane = tid & 63;
    int wv   = tid >> 6;
    if (lane == 0) {
#pragma unroll
        for (int m = 0; m < M; ++m) lsm[wv][m] = sm[m];
    }
    __syncthreads();
    if (tid < M) {
        float a = 0.0f;
#pragma unroll
        for (int k = 0; k < 8; ++k) a += lsm[k][tid];
        atomicAdd(&facc[tid], a);
    }
}

// ---------------------------------------------------------------------------
// final head: out[3] = concat(f[10], x_group@Wg[4]) @ Wm
// ---------------------------------------------------------------------------
__global__ void final_kernel(const float* __restrict__ facc,
                             const float* __restrict__ xg,
                             const float* __restrict__ Wg,
                             const float* __restrict__ Wm,
                             float* __restrict__ out)
{
    if (threadIdx.x == 0 && blockIdx.x == 0) {
        float go[4];
        for (int g = 0; g < 4; ++g) {
            float a = 0.0f;
            for (int i = 0; i < 14; ++i) a += xg[i] * Wg[i * 4 + g];
            go[g] = a;
        }
        for (int j = 0; j < 3; ++j) {
            float o = 0.0f;
            for (int k = 0; k < M; ++k) o += facc[k] * Wm[k * 3 + j];
            for (int g = 0; g < 4; ++g)  o += go[g] * Wm[(M + g) * 3 + j];
            out[j] = o;
        }
    }
}

extern "C" void kernel_launch(void* const* d_in, const int* in_sizes, int n_in,
                              void* d_out, int out_size, void* d_ws, size_t ws_size,
                              hipStream_t stream)
{
    const float* x_member = (const float*)d_in[0];
    const float* x_group  = (const float*)d_in[1];
    const int*   edge_src = (const int*)  d_in[2];
    const int*   edge_dst = (const int*)  d_in[3];
    const float* H0       = (const float*)d_in[4];
    const float* Hs       = (const float*)d_in[5];
    const float* Wsc      = (const float*)d_in[6];
    const float* Wg       = (const float*)d_in[7];
    const float* Wm       = (const float*)d_in[8];
    float* out = (float*)d_out;

    // workspace layout — 36.1 MB (gh+bsum live through all rounds):
    //   col/ebuf : 25,600,000 B
    //   gh       :    800,768 B  (GHLEN ints)  @ 25,600,000
    //   bsum     :        784 B                @ 26,400,768
    //   xh       :  3,200,000 B  [N] fp16x8    @ 26,420,000
    //   r0b      :  3,200,000 B  [N] fp8x16    @ 29,620,000
    //   r1b      :  3,200,000 B  [N] fp8x16    @ 32,820,000
    //   facc     :         64 B                @ 36,020,000
    char* w = (char*)d_ws;
    int*    col  = (int*)w;
    int*    gh   = (int*)(w + 25600000);
    int*    bsum = gh + GHLEN;
    __half* xh   = (__half*)(w + 26420000);
    u32x4*  r0b  = (u32x4*)(w + 29620000);
    u32x4*  r1b  = (u32x4*)(w + 32820000);
    float*  facc = (float*)(w + 36020000);

    // raise dynamic-LDS cap for passC (host-side attr, graph-capture safe)
    static bool attr_done = false;
    if (!attr_done) {
        (void)hipFuncSetAttribute((const void*)passC_kernel,
                                  hipFuncAttributeMaxDynamicSharedMemorySize,
                                  PASSC_LDS_BYTES);
        attr_done = true;
    }

    (void)hipMemsetAsync(facc, 0, 64, stream);

    passA_kernel<<<NBLK, 1024, 0, stream>>>(edge_dst, gh, x_member, xh);
    scan1_kernel<<<SBLOCKS, 1024, 0, stream>>>(gh, bsum);
    scan2_kernel<<<1, 256, 0, stream>>>(bsum);
    passC_kernel<<<NBLK, 1024, PASSC_LDS_BYTES, stream>>>(edge_src, edge_dst, gh, bsum, col);

    round_kernel<T, false><<<NB, 512, 0, stream>>>((const u32x4*)xh, gh, bsum, col, r0b, H0,             Wsc, 0, facc);
    round_kernel<M, true ><<<NB, 512, 0, stream>>>(r0b,              gh, bsum, col, r1b, Hs + 0 * M * M, Wsc, 1, facc);
    round_kernel<M, true ><<<NB, 512, 0, stream>>>(r1b,              gh, bsum, col, r0b, Hs + 1 * M * M, Wsc, 2, facc);
    round_kernel<M, true ><<<NB, 512, 0, stream>>>(r0b,              gh, bsum, col, r1b, Hs + 2 * M * M, Wsc, 3, facc);

    final_kernel<<<1, 64, 0, stream>>>(facc, x_group, Wg, Wm, out);
}

// Round 10
// 321.728 us; speedup vs baseline: 1.5658x; 1.5658x over previous
//
#include <hip/hip_runtime.h>
#include <hip/hip_fp16.h>
#include <math.h>

#define N_NODES 200000
#define N_EDGES 6400000
#define T 6
#define M 10

// CSR build configuration: 256-node buckets, chunked counting sort.
#define NB    782            // ceil(200000/256) buckets (dst>>8)
#define NBLK  256            // edge chunks == CU count
#define CH    25000          // edges per chunk (256*25000 = 6.4M exact)
#define GHLEN (NB * NBLK)    // 200192

#define SBLOCKS 196          // ceil(GHLEN/1024) scan blocks

// passC dynamic LDS: edge array (CH) + cnt/ls/lcur/gs (4*NB) + scan buf (1024)
#define PASSC_LDS_INTS  (CH + 4 * NB + 1024)
#define PASSC_LDS_BYTES (PASSC_LDS_INTS * 4)   // 116,608 B < 160 KiB/CU

#define QSCALE  262144.0f    // 2^18 signed fixed-point (round 0; |sum| small)
#define QINV    (1.0f / 262144.0f)
#define PSCALE  512.0f       // u16-pair fixed point (fp8 rounds, values in (0,1))
#define PINV    (1.0f / 512.0f)

typedef __attribute__((ext_vector_type(2))) float vf2;
typedef __attribute__((ext_vector_type(4))) unsigned int u32x4;

// ---------------------------------------------------------------------------
// Pass A (+ fused convert): per-chunk bucket histogram -> gh[bucket*NBLK+g],
// and x_member [N,6] fp32 -> xh [N,8] fp16 conversion.
// NOTE r9: hipLaunchCooperativeKernel silently no-ops under this harness's
// graph capture (absmax = |ref|, outputs never written) -> REGULAR launches
// only; kernel boundaries are the global barriers.
// ---------------------------------------------------------------------------
__global__ __launch_bounds__(1024) void passA_kernel(
    const int* __restrict__ dst, int* __restrict__ gh,
    const float* __restrict__ x, __half* __restrict__ xh)
{
    __shared__ int lh[NB];
    int g   = blockIdx.x;
    int tid = threadIdx.x;

    // fused convert: 256*1024 = 262144 >= N_NODES, single stride
    int i = g * 1024 + tid;
    if (i < N_NODES) {
        const vf2* p = (const vf2*)(x + (size_t)i * 6);   // rows 24B, 8B aligned
        vf2 a = __builtin_nontemporal_load(p);
        vf2 b = __builtin_nontemporal_load(p + 1);
        vf2 c = __builtin_nontemporal_load(p + 2);
        union { __half2 h[4]; u32x4 q; } u;
        u.h[0] = __floats2half2_rn(a.x, a.y);
        u.h[1] = __floats2half2_rn(b.x, b.y);
        u.h[2] = __floats2half2_rn(c.x, c.y);
        u.h[3] = __floats2half2_rn(0.f, 0.f);
        __builtin_nontemporal_store(u.q, (u32x4*)(xh + (size_t)i * 8));
    }

    for (int t = tid; t < NB; t += 1024) lh[t] = 0;
    __syncthreads();
    int base = g * CH;
    int end  = base + CH; if (end > N_EDGES) end = N_EDGES;
    for (int e = base + tid; e < end; e += 1024)
        atomicAdd(&lh[__builtin_nontemporal_load(dst + e) >> 8], 1);
    __syncthreads();
    for (int t = tid; t < NB; t += 1024) gh[t * NBLK + g] = lh[t];
}

// ---------------------------------------------------------------------------
// Hierarchical exclusive scan of gh[GHLEN].
// scan3 DELETED: consumers add bsum[idx>>10] themselves.
// ---------------------------------------------------------------------------
__global__ __launch_bounds__(1024) void scan1_kernel(
    int* __restrict__ gh, int* __restrict__ bsum)
{
    __shared__ int sbuf[1024];
    int tid = threadIdx.x;
    int t   = blockIdx.x * 1024 + tid;
    int v   = (t < GHLEN) ? gh[t] : 0;
    sbuf[tid] = v;
    __syncthreads();
    for (int d = 1; d < 1024; d <<= 1) {
        int u = (tid >= d) ? sbuf[tid - d] : 0;
        __syncthreads();
        sbuf[tid] += u;
        __syncthreads();
    }
    if (t < GHLEN) gh[t] = sbuf[tid] - v;           // local exclusive
    if (tid == 1023) bsum[blockIdx.x] = sbuf[1023]; // block total
}

__global__ __launch_bounds__(256) void scan2_kernel(int* __restrict__ bsum)
{
    __shared__ int sbuf[256];
    int tid = threadIdx.x;
    int v = (tid < SBLOCKS) ? bsum[tid] : 0;
    sbuf[tid] = v;
    __syncthreads();
    for (int d = 1; d < 256; d <<= 1) {
        int u = (tid >= d) ? sbuf[tid - d] : 0;
        __syncthreads();
        sbuf[tid] += u;
        __syncthreads();
    }
    if (tid < SBLOCKS) bsum[tid] = sbuf[tid] - v;   // exclusive
}

// ---------------------------------------------------------------------------
// Pass C: counting-sort the whole chunk INSIDE LDS, then copy each
// (bucket,chunk) segment out as a contiguous per-wave burst (full-line,
// write-once; scattered 4 B stores cost 5.9x write amp at HBM).
// ---------------------------------------------------------------------------
__global__ __launch_bounds__(1024) void passC_kernel(
    const int* __restrict__ src, const int* __restrict__ dst,
    const int* __restrict__ gh, const int* __restrict__ bsum,
    int* __restrict__ ebuf)
{
    extern __shared__ int dyn[];
    int* earr = dyn;             // [CH]  bucket-sorted packed edges
    int* cnt  = dyn + CH;        // [NB]  edges of bucket b in this chunk
    int* ls   = cnt + NB;        // [NB]  local exclusive start
    int* lcur = ls + NB;         // [NB]  scatter cursor
    int* gs   = lcur + NB;       // [NB]  global segment start
    int* sbuf = gs + NB;         // [1024] scan temp

    int g   = blockIdx.x;
    int tid = threadIdx.x;

    // per-bucket global start + count for this chunk (bsum fold: no scan3)
    for (int b = tid; b < NB; b += 1024) {
        int idx = b * NBLK + g;
        int s0  = gh[idx] + bsum[idx >> 10];
        int s1  = (idx + 1 < GHLEN) ? gh[idx + 1] + bsum[(idx + 1) >> 10]
                                    : N_EDGES;
        gs[b]  = s0;
        cnt[b] = s1 - s0;
    }
    __syncthreads();

    // exclusive scan of cnt -> ls (NB=782 <= 1024, single pass)
    int v = (tid < NB) ? cnt[tid] : 0;
    sbuf[tid] = v;
    __syncthreads();
    for (int d = 1; d < 1024; d <<= 1) {
        int u = (tid >= d) ? sbuf[tid - d] : 0;
        __syncthreads();
        sbuf[tid] += u;
        __syncthreads();
    }
    if (tid < NB) { int e0 = sbuf[tid] - v; ls[tid] = e0; lcur[tid] = e0; }
    __syncthreads();

    // scatter chunk edges into LDS, bucket-grouped (LDS atomics only)
    int base = g * CH;
    for (int e = base + tid; e < base + CH; e += 1024) {
        int s = __builtin_nontemporal_load(src + e);
        int d = __builtin_nontemporal_load(dst + e);
        int b = d >> 8;
        int p = atomicAdd(&lcur[b], 1);
        earr[p] = (s << 8) | (d & 255);
    }
    __syncthreads();

    // coalesced copy-out: one wave per bucket segment (mean 32 edges = 128 B)
    int wv = tid >> 6, lane = tid & 63;
    for (int b = wv; b < NB; b += 16) {
        int bl = ls[b], bg = gs[b], c = cnt[b];
        for (int o = lane; o < c; o += 64)
            ebuf[bg + o] = earr[bl + o];   // normal store: L2 merges the
    }                                      // chunk-boundary-shared lines
}

// ---------------------------------------------------------------------------
// round, v8 (= r8 minus the NT poison): scatter-accumulate into per-dst LDS
// accumulators.
//
// Settled evidence:
//  - gather floor ~4.8 cyc per random 16B L2-hit gather; insensitive to
//    occupancy (27/29/40%), ILP (4/8-deep), and cache policy (NT: r8
//    FETCH 25.5->41 MB, +40% time -> table must stay L2-resident; normal
//    loads only). ACCEPTED as floor; do not re-attack.
//  - direct __shared__ int atomics -> native ds_add (r4: float* param ->
//    flat path, 8x slower).
//  - fp8 rounds: u16-pair packed x512 (5 atomics/edge; conflicts halved,
//    r7-verified). Round 0: TD signed 2^18 atomics.
//  - 4-deep gather pipeline (VGPR ~28, occ ~40%); 8-deep raised VGPR to 48
//    and gave nothing (r7).
// ---------------------------------------------------------------------------
template<int TD, bool FP8IN>
__device__ __forceinline__ void decode_row(u32x4 q, float* f)
{
    if (FP8IN) {
        vf2 f0 = __builtin_amdgcn_cvt_pk_f32_fp8(q.x, false);
        vf2 f1 = __builtin_amdgcn_cvt_pk_f32_fp8(q.x, true);
        vf2 f2 = __builtin_amdgcn_cvt_pk_f32_fp8(q.y, false);
        vf2 f3 = __builtin_amdgcn_cvt_pk_f32_fp8(q.y, true);
        vf2 f4 = __builtin_amdgcn_cvt_pk_f32_fp8(q.z, false);
        f[0] = f0.x; f[1] = f0.y; f[2] = f1.x; f[3] = f1.y;
        f[4] = f2.x; f[5] = f2.y; f[6] = f3.x; f[7] = f3.y;
        f[8] = f4.x; f[9] = f4.y;
    } else {
        union { u32x4 q; __half2 h[8]; } u; u.q = q;
#pragma unroll
        for (int k = 0; k < TD / 2; ++k) {
            float2 d = __half22float2(u.h[k]);
            f[2 * k] = d.x; f[2 * k + 1] = d.y;
        }
    }
}

// register-only: decode a row and produce the NA packed addends
template<int TD, bool FP8IN, int NA>
__device__ __forceinline__ void pack_row(u32x4 q, unsigned int* pk)
{
    float f[TD];
    decode_row<TD, FP8IN>(q, f);
    if (FP8IN) {
#pragma unroll
        for (int k = 0; k < 5; ++k)
            pk[k] = __float2uint_rn(f[2 * k] * PSCALE)
                  | (__float2uint_rn(f[2 * k + 1] * PSCALE) << 16);
    } else {
#pragma unroll
        for (int t = 0; t < TD; ++t)
            pk[t] = (unsigned int)__float2int_rn(f[t] * QSCALE);
    }
}

template<int TD, bool FP8IN>
__global__ __launch_bounds__(512) void round_kernel(
    const u32x4* __restrict__ in,      // [N] 16 B rows (fp16x8 or fp8x16)
    const int*   __restrict__ gh,      // scanned (bucket,chunk) offsets (local)
    const int*   __restrict__ bsum,    // scan block offsets (scan3 folded)
    const int*   __restrict__ col,     // packed (src<<8)|dstlow, bucket-grouped
    u32x4*       __restrict__ rout,    // [N] 16 B fp8 rows
    const float* __restrict__ H,       // [TD, M]
    const float* __restrict__ Wsc, int widx,
    float*       __restrict__ facc)
{
    constexpr int QST = FP8IN ? 5 : 7;     // acc stride (gcd(QST,32)=1)
    constexpr int NA  = FP8IN ? 5 : T;     // atomics per edge
    __shared__ unsigned int qacc[256 * QST];
    __shared__ int   shb[2];
    __shared__ float lsm[8][M];

    int b   = blockIdx.x;
    int tid = threadIdx.x;

    for (int k = tid; k < 256 * QST; k += 512) qacc[k] = 0u;
    if (tid == 0) {
        int i0 = b * NBLK;
        shb[0] = gh[i0] + bsum[i0 >> 10];
        if (b == NB - 1) shb[1] = N_EDGES;
        else {
            int i1 = (b + 1) * NBLK;
            shb[1] = gh[i1] + bsum[i1 >> 10];
        }
    }
    __syncthreads();
    int e0 = shb[0], e1 = shb[1];
    int e0a = (e0 + 3) & ~3;            // align for dwordx4
    if (e0a > e1) e0a = e1;
    int nvec = (e1 - e0a) >> 2;

    // head (<=3 edges)
    for (int k = e0 + tid; k < e0a; k += 512) {
        int e = __builtin_nontemporal_load(col + k);
        unsigned int pk[NA];
        pack_row<TD, FP8IN, NA>(in[e >> 8], pk);
        int a0 = (e & 255) * QST;
#pragma unroll
        for (int t = 0; t < NA; ++t) atomicAdd(&qacc[a0 + t], pk[t]);
    }
    // main: 4 packed edges per lane-iter, 4 gathers in flight (NORMAL loads:
    // table stays L2-resident; NT here cost +40% in r8)
    const u32x4* colv = (const u32x4*)(col + e0a);
    for (int g = tid; g < nvec; g += 512) {
        u32x4 ee = __builtin_nontemporal_load(colv + g);
        int ex = (int)ee.x, ey = (int)ee.y, ez = (int)ee.z, ew = (int)ee.w;
        u32x4 q0 = in[ex >> 8];
        u32x4 q1 = in[ey >> 8];
        u32x4 q2 = in[ez >> 8];
        u32x4 q3 = in[ew >> 8];
        unsigned int pk[NA];
        pack_row<TD, FP8IN, NA>(q0, pk);
        int a0 = (ex & 255) * QST;
#pragma unroll
        for (int t = 0; t < NA; ++t) atomicAdd(&qacc[a0 + t], pk[t]);
        pack_row<TD, FP8IN, NA>(q1, pk);
        a0 = (ey & 255) * QST;
#pragma unroll
        for (int t = 0; t < NA; ++t) atomicAdd(&qacc[a0 + t], pk[t]);
        pack_row<TD, FP8IN, NA>(q2, pk);
        a0 = (ez & 255) * QST;
#pragma unroll
        for (int t = 0; t < NA; ++t) atomicAdd(&qacc[a0 + t], pk[t]);
        pack_row<TD, FP8IN, NA>(q3, pk);
        a0 = (ew & 255) * QST;
#pragma unroll
        for (int t = 0; t < NA; ++t) atomicAdd(&qacc[a0 + t], pk[t]);
    }
    // tail (<=3 edges)
    for (int k = e0a + nvec * 4 + tid; k < e1; k += 512) {
        int e = __builtin_nontemporal_load(col + k);
        unsigned int pk[NA];
        pack_row<TD, FP8IN, NA>(in[e >> 8], pk);
        int a0 = (e & 255) * QST;
#pragma unroll
        for (int t = 0; t < NA; ++t) atomicAdd(&qacc[a0 + t], pk[t]);
    }
    __syncthreads();

    float w = Wsc[widx];
    float sm[M];
    int i = b * 256 + tid;

    if (tid < 256 && i < N_NODES) {
        float self[TD];
        decode_row<TD, FP8IN>(in[i], self);
        float v[TD];
        if (FP8IN) {
#pragma unroll
            for (int k = 0; k < 5; ++k) {
                unsigned int q = qacc[tid * QST + k];
                v[2 * k]     = (float)(q & 0xFFFFu) * PINV + self[2 * k];
                v[2 * k + 1] = (float)(q >> 16)     * PINV + self[2 * k + 1];
            }
        } else {
#pragma unroll
            for (int t = 0; t < TD; ++t)
                v[t] = (float)(int)qacc[tid * QST + t] * QINV + self[t];
        }

        float z[M];
#pragma unroll
        for (int m = 0; m < M; ++m) {
            float a = 0.0f;
#pragma unroll
            for (int t = 0; t < TD; ++t) a += v[t] * H[t * M + m];
            z[m] = a;
        }
        float rr[M];
        float ssum = 0.0f;
#pragma unroll
        for (int m = 0; m < M; ++m) {
            rr[m] = 1.0f / (1.0f + __expf(-z[m]));
            sm[m] = __expf(rr[m] * w);            // rr*w in (0,0.2): no max shift
            ssum += sm[m];
        }
        {
            int d0 = __builtin_amdgcn_cvt_pk_fp8_f32(rr[0], rr[1], 0, false);
            d0     = __builtin_amdgcn_cvt_pk_fp8_f32(rr[2], rr[3], d0, true);
            int d1 = __builtin_amdgcn_cvt_pk_fp8_f32(rr[4], rr[5], 0, false);
            d1     = __builtin_amdgcn_cvt_pk_fp8_f32(rr[6], rr[7], d1, true);
            int d2 = __builtin_amdgcn_cvt_pk_fp8_f32(rr[8], rr[9], 0, false);
            u32x4 o = { (unsigned)d0, (unsigned)d1, (unsigned)d2, 0u };
            __builtin_nontemporal_store(o, rout + i);
        }
        float inv = 1.0f / ssum;
#pragma unroll
        for (int m = 0; m < M; ++m) sm[m] *= inv;
    } else {
#pragma unroll
        for (int m = 0; m < M; ++m) sm[m] = 0.0f;
    }

    // wave-64 shuffle reduction of the 10 softmax sums (8 waves)
#pragma unroll
    for (int m = 0; m < M; ++m) {
        float x = sm[m];
#pragma unroll
        for (int o = 32; o > 0; o >>= 1) x += __shfl_down(x, o);
        sm[m] = x;
    }
    int lane = tid & 63;
    int wv   = tid >> 6;
    if (lane == 0) {
#pragma unroll
        for (int m = 0; m < M; ++m) lsm[wv][m] = sm[m];
    }
    __syncthreads();
    if (tid < M) {
        float a = 0.0f;
#pragma unroll
        for (int k = 0; k < 8; ++k) a += lsm[k][tid];
        atomicAdd(&facc[tid], a);
    }
}

// ---------------------------------------------------------------------------
// final head: out[3] = concat(f[10], x_group@Wg[4]) @ Wm
// ---------------------------------------------------------------------------
__global__ void final_kernel(const float* __restrict__ facc,
                             const float* __restrict__ xg,
                             const float* __restrict__ Wg,
                             const float* __restrict__ Wm,
                             float* __restrict__ out)
{
    if (threadIdx.x == 0 && blockIdx.x == 0) {
        float go[4];
        for (int g = 0; g < 4; ++g) {
            float a = 0.0f;
            for (int i = 0; i < 14; ++i) a += xg[i] * Wg[i * 4 + g];
            go[g] = a;
        }
        for (int j = 0; j < 3; ++j) {
            float o = 0.0f;
            for (int k = 0; k < M; ++k) o += facc[k] * Wm[k * 3 + j];
            for (int g = 0; g < 4; ++g)  o += go[g] * Wm[(M + g) * 3 + j];
            out[j] = o;
        }
    }
}

extern "C" void kernel_launch(void* const* d_in, const int* in_sizes, int n_in,
                              void* d_out, int out_size, void* d_ws, size_t ws_size,
                              hipStream_t stream)
{
    const float* x_member = (const float*)d_in[0];
    const float* x_group  = (const float*)d_in[1];
    const int*   edge_src = (const int*)  d_in[2];
    const int*   edge_dst = (const int*)  d_in[3];
    const float* H0       = (const float*)d_in[4];
    const float* Hs       = (const float*)d_in[5];
    const float* Wsc      = (const float*)d_in[6];
    const float* Wg       = (const float*)d_in[7];
    const float* Wm       = (const float*)d_in[8];
    float* out = (float*)d_out;

    // workspace layout — 36.1 MB (gh+bsum live through all rounds):
    //   col/ebuf : 25,600,000 B
    //   gh       :    800,768 B  (GHLEN ints)  @ 25,600,000
    //   bsum     :        784 B                @ 26,400,768
    //   xh       :  3,200,000 B  [N] fp16x8    @ 26,420,000
    //   r0b      :  3,200,000 B  [N] fp8x16    @ 29,620,000
    //   r1b      :  3,200,000 B  [N] fp8x16    @ 32,820,000
    //   facc     :         64 B                @ 36,020,000
    char* w = (char*)d_ws;
    int*    col  = (int*)w;
    int*    gh   = (int*)(w + 25600000);
    int*    bsum = gh + GHLEN;
    __half* xh   = (__half*)(w + 26420000);
    u32x4*  r0b  = (u32x4*)(w + 29620000);
    u32x4*  r1b  = (u32x4*)(w + 32820000);
    float*  facc = (float*)(w + 36020000);

    // raise dynamic-LDS cap for passC (host-side attr, graph-capture safe)
    static bool attr_done = false;
    if (!attr_done) {
        (void)hipFuncSetAttribute((const void*)passC_kernel,
                                  hipFuncAttributeMaxDynamicSharedMemorySize,
                                  PASSC_LDS_BYTES);
        attr_done = true;
    }

    (void)hipMemsetAsync(facc, 0, 64, stream);

    passA_kernel<<<NBLK, 1024, 0, stream>>>(edge_dst, gh, x_member, xh);
    scan1_kernel<<<SBLOCKS, 1024, 0, stream>>>(gh, bsum);
    scan2_kernel<<<1, 256, 0, stream>>>(bsum);
    passC_kernel<<<NBLK, 1024, PASSC_LDS_BYTES, stream>>>(edge_src, edge_dst, gh, bsum, col);

    round_kernel<T, false><<<NB, 512, 0, stream>>>((const u32x4*)xh, gh, bsum, col, r0b, H0,             Wsc, 0, facc);
    round_kernel<M, true ><<<NB, 512, 0, stream>>>(r0b,              gh, bsum, col, r1b, Hs + 0 * M * M, Wsc, 1, facc);
    round_kernel<M, true ><<<NB, 512, 0, stream>>>(r1b,              gh, bsum, col, r0b, Hs + 1 * M * M, Wsc, 2, facc);
    round_kernel<M, true ><<<NB, 512, 0, stream>>>(r0b,              gh, bsum, col, r1b, Hs + 2 * M * M, Wsc, 3, facc);

    final_kernel<<<1, 64, 0, stream>>>(facc, x_group, Wg, Wm, out);
}